// Round 6
// baseline (177.295 us; speedup 1.0000x reference)
//
#include <hip/hip_runtime.h>
#include <cstdint>
#include <cstddef>

#define NB 16
#define NC 256
#define NN 4096
#define ND 256

typedef unsigned short u16;
typedef unsigned int u32;

typedef __attribute__((ext_vector_type(8))) short short8;
typedef __attribute__((ext_vector_type(4))) float f32x4;

__device__ __forceinline__ u16 f2bf(float f) {
  union { float f; u32 u; } v; v.f = f;
  u32 r = v.u + 0x7FFFu + ((v.u >> 16) & 1u);
  return (u16)(r >> 16);
}
__device__ __forceinline__ float bf2f(u16 h) {
  union { u32 u; float f; } v; v.u = ((u32)h) << 16; return v.f;
}

// ---------------------------------------------------------------------------
// Kernel 1 (round-3 verified, unchanged): per (b, n-tile of 64) block, full C.
// Thread micro-tile 8c x 8n; float4 coalesced loads; register-renaming
// transpose -> short8 16B xbT stores; conflict-free LDS q-reduce; in-wave
// shfl softmax partials (m,l) and pacc; Wv bf16 cast folded into 8 blocks.
// ---------------------------------------------------------------------------
__global__ __launch_bounds__(256) void k_fuse1(const float* __restrict__ x,
                                               const float* __restrict__ W,
                                               u16* __restrict__ xbT,
                                               u16* __restrict__ wvb,
                                               float* __restrict__ pm,
                                               float* __restrict__ pl,
                                               float* __restrict__ pacc) {
  __shared__ float qred[32 * 65];   // 8,320 B, bank-conflict-free
  __shared__ float qred2[4 * 65];   // 1,040 B
  const int t = threadIdx.x;
  const int b = blockIdx.y, n0 = blockIdx.x * 64;
  const int tx = t & 7, ty = t >> 3;        // tx: n-group 0..7, ty: c-group 0..31
  const int c0 = ty * 8, nl = tx * 8;
  const float* xb = x + (size_t)b * NC * NN + n0;

  const float4 w0 = *(const float4*)(W + c0);
  const float4 w1 = *(const float4*)(W + c0 + 4);
  const float wq[8] = {w0.x, w0.y, w0.z, w0.w, w1.x, w1.y, w1.z, w1.w};

  short8 pk[8];          // pk[j] = bf16 x[c0..c0+8][nl+j]  (transposed packs)
  float qp[8] = {0.f, 0.f, 0.f, 0.f, 0.f, 0.f, 0.f, 0.f};

#pragma unroll
  for (int r = 0; r < 8; ++r) {
    const float* xr = xb + (size_t)(c0 + r) * NN + nl;
    const float4 va = *(const float4*)(xr);
    const float4 vb = *(const float4*)(xr + 4);
    qp[0] += wq[r] * va.x; qp[1] += wq[r] * va.y;
    qp[2] += wq[r] * va.z; qp[3] += wq[r] * va.w;
    qp[4] += wq[r] * vb.x; qp[5] += wq[r] * vb.y;
    qp[6] += wq[r] * vb.z; qp[7] += wq[r] * vb.w;
    pk[0][r] = (short)f2bf(va.x); pk[1][r] = (short)f2bf(va.y);
    pk[2][r] = (short)f2bf(va.z); pk[3][r] = (short)f2bf(va.w);
    pk[4][r] = (short)f2bf(vb.x); pk[5][r] = (short)f2bf(vb.y);
    pk[6][r] = (short)f2bf(vb.z); pk[7][r] = (short)f2bf(vb.w);
  }

  u16* ob = xbT + (size_t)(b * NN + n0 + nl) * NC + c0;
#pragma unroll
  for (int j = 0; j < 8; ++j)
    *(short8*)(ob + (size_t)j * NC) = pk[j];

#pragma unroll
  for (int j = 0; j < 8; ++j) qred[ty * 65 + nl + j] = qp[j];
  __syncthreads();
  {
    const int n = t & 63, g = t >> 6;
    float s = 0.f;
#pragma unroll
    for (int k = 0; k < 8; ++k) s += qred[(g * 8 + k) * 65 + n];
    qred2[g * 65 + n] = s;
  }
  __syncthreads();

  float q[8];
#pragma unroll
  for (int j = 0; j < 8; ++j)
    q[j] = qred2[0 * 65 + nl + j] + qred2[1 * 65 + nl + j] +
           qred2[2 * 65 + nl + j] + qred2[3 * 65 + nl + j];

  float m = q[0];
#pragma unroll
  for (int j = 1; j < 8; ++j) m = fmaxf(m, q[j]);
#pragma unroll
  for (int off = 1; off < 8; off <<= 1) m = fmaxf(m, __shfl_xor(m, off));

  float p[8]; float l = 0.f;
#pragma unroll
  for (int j = 0; j < 8; ++j) { p[j] = __expf(q[j] - m); l += p[j]; }
#pragma unroll
  for (int off = 1; off < 8; off <<= 1) l += __shfl_xor(l, off);

  float sc[8];
#pragma unroll
  for (int r = 0; r < 8; ++r) {
    float s = 0.f;
#pragma unroll
    for (int j = 0; j < 8; ++j) s += bf2f((u16)pk[j][r]) * p[j];
    sc[r] = s;
  }
#pragma unroll
  for (int off = 1; off < 8; off <<= 1) {
#pragma unroll
    for (int r = 0; r < 8; ++r) sc[r] += __shfl_xor(sc[r], off);
  }
  if (tx == 0) {
    float* pp = pacc + ((size_t)b * 64 + blockIdx.x) * NC + c0;
#pragma unroll
    for (int r = 0; r < 8; ++r) pp[r] = sc[r];
  }
  if (t == 0) {
    pm[b * 64 + blockIdx.x] = m;
    pl[b * 64 + blockIdx.x] = l;
  }

  if (b == 0 && blockIdx.x < 8) {
    const float* wv = W + (size_t)(1 + ND) * NC;
    const int base = blockIdx.x * 8192;
#pragma unroll
    for (int i = 0; i < 8; ++i) {
      const int idx = base + i * 1024 + t * 4;
      const float4 v = *(const float4*)(wv + idx);
      ushort4 o = {f2bf(v.x), f2bf(v.y), f2bf(v.z), f2bf(v.w)};
      *(ushort4*)(wvb + idx) = o;
    }
  }
}

// ---------------------------------------------------------------------------
// Kernel 2: fused combine + GEMM, NO LDS STAGING.
//  Combine (prologue): redundantly per block, 64 softmax partials -> xs ->
//  ctx (pacc + W via L2).  One syncthreads, then a barrier-free K-loop:
//  MFMA fragments loaded DIRECTLY from global -- A (wvb, 128KB) is
//  L2-resident; B (xbT) is streamed once, each fragment read covering a full
//  64B-aligned segment (row stride 512B, quad*16B contiguous within 64B).
//  8 independent K-chunks of {8 dwordx4 loads + 16 MFMA}: compiler
//  software-pipelines; latency hidden by ILP + 4 blocks/CU (LDS ~3.3KB).
//  Operand roles swapped (round-5 verified): D row = n, col = d ->
//  f32x4 nontemporal epilogue stores.
// ---------------------------------------------------------------------------
#define BN 128

__global__ __launch_bounds__(512) void k_gemm(const u16* __restrict__ xbT,
                                              const u16* __restrict__ wvb,
                                              const float* __restrict__ W,
                                              const float* __restrict__ pm,
                                              const float* __restrict__ pl,
                                              const float* __restrict__ pacc,
                                              float* __restrict__ out) {
  __shared__ float am[64], al[64];
  __shared__ __align__(16) float sx[NC];
  __shared__ float sctx[NC];

  const int t = threadIdx.x;
  const int b = blockIdx.y;
  const int n0 = blockIdx.x * BN;
  const int lane = t & 63, w = t >> 6;
  const int wd = (w >> 1) * 64, wn = (w & 1) * 64;
  const int quad = lane >> 4, l15 = lane & 15;

  // ---- combine: partials -> xs -> ctx ----
  if (t < 64) { am[t] = pm[b * 64 + t]; al[t] = pl[b * 64 + t]; }
  __syncthreads();
  float M2 = -3.4e38f;
#pragma unroll
  for (int i = 0; i < 64; ++i) M2 = fmaxf(M2, am[i]);
  if (t < 256) {
    float xsv = 0.f, L2s = 0.f;
#pragma unroll 8
    for (int i = 0; i < 64; ++i) {
      const float wgt = __expf(am[i] - M2);
      L2s += wgt * al[i];
      xsv += wgt * pacc[(size_t)(b * 64 + i) * NC + t];
    }
    sx[t] = xsv / L2s;
  }
  __syncthreads();
  if (t < 256) {
    const float* wk = W + (size_t)(1 + t) * NC;
    float a = 0.f;
#pragma unroll 4
    for (int c4 = 0; c4 < 64; ++c4) {
      const float4 w4 = *(const float4*)(wk + c4 * 4);
      const float4 s4 = *(const float4*)&sx[c4 * 4];
      a += w4.x * s4.x + w4.y * s4.y + w4.z * s4.z + w4.w * s4.w;
    }
    sctx[t] = a;
  }
  __syncthreads();   // sctx visible to all waves (no K-loop barriers anymore!)

  // ---- barrier-free GEMM main loop, fragments direct from global ----
  f32x4 acc[4][4];   // acc[ni][mi]: ni = n-subtile, mi = d-subtile
#pragma unroll
  for (int ni = 0; ni < 4; ++ni)
#pragma unroll
    for (int mi = 0; mi < 4; ++mi)
      acc[ni][mi] = (f32x4){0.f, 0.f, 0.f, 0.f};

  const u16* pA = wvb + (size_t)(wd + l15) * NC + quad * 8;
  const u16* pB = xbT + (size_t)(b * NN + n0 + wn + l15) * NC + quad * 8;

#pragma unroll
  for (int kc = 0; kc < 8; ++kc) {
    short8 xf[4], wf[4];
#pragma unroll
    for (int ni = 0; ni < 4; ++ni)
      xf[ni] = *(const short8*)(pB + (size_t)(ni * 16) * NC + kc * 32);
#pragma unroll
    for (int mi = 0; mi < 4; ++mi)
      wf[mi] = *(const short8*)(pA + (size_t)(mi * 16) * NC + kc * 32);
#pragma unroll
    for (int ni = 0; ni < 4; ++ni)
#pragma unroll
      for (int mi = 0; mi < 4; ++mi)
        acc[ni][mi] = __builtin_amdgcn_mfma_f32_16x16x32_bf16(xf[ni], wf[mi],
                                                              acc[ni][mi], 0, 0, 0);
  }

  // ---- epilogue: D row = n (quad*4+r), col = d (l15) -> f32x4 stores ----
#pragma unroll
  for (int mi = 0; mi < 4; ++mi) {
    const int d = wd + mi * 16 + l15;
    const float cx = sctx[d];
    float* op = out + (size_t)(b * NC + d) * NN + n0 + wn + quad * 4;
#pragma unroll
    for (int ni = 0; ni < 4; ++ni) {
      f32x4 v = acc[ni][mi];
      v[0] = fmaxf(v[0], 0.f) * cx;
      v[1] = fmaxf(v[1], 0.f) * cx;
      v[2] = fmaxf(v[2], 0.f) * cx;
      v[3] = fmaxf(v[3], 0.f) * cx;
      __builtin_nontemporal_store(v, (f32x4*)(op + ni * 16));
    }
  }
}

// ---------------------------------------------------------------------------
extern "C" void kernel_launch(void* const* d_in, const int* in_sizes, int n_in,
                              void* d_out, int out_size, void* d_ws, size_t ws_size,
                              hipStream_t stream) {
  const float* x = (const float*)d_in[0];
  const float* W = (const float*)d_in[1];
  float* out = (float*)d_out;

  char* ws = (char*)d_ws;
  u16* xbT    = (u16*)ws;                                 // 33,554,432 B
  float* pacc = (float*)(ws + 33554432);                  //  1,048,576 B
  float* pm   = (float*)(ws + 34603008);                  //      4,096 B
  float* pl   = (float*)(ws + 34607104);                  //      4,096 B
  u16* wvb    = (u16*)(ws + 34611200);                    //    131,072 B

  k_fuse1<<<dim3(64, 16), 256, 0, stream>>>(x, W, xbT, wvb, pm, pl, pacc);
  k_gemm<<<dim3(32, 16), 512, 0, stream>>>(xbT, wvb, W, pm, pl, pacc, out);
}

// Round 8
// 173.686 us; speedup vs baseline: 1.0208x; 1.0208x over previous
//
#include <hip/hip_runtime.h>
#include <cstdint>
#include <cstddef>

#define NB 16
#define NC 256
#define NN 4096
#define ND 256

typedef unsigned short u16;
typedef unsigned int u32;

typedef __attribute__((ext_vector_type(8))) short short8;
typedef __attribute__((ext_vector_type(4))) float f32x4;

__device__ __forceinline__ u16 f2bf(float f) {
  union { float f; u32 u; } v; v.f = f;
  u32 r = v.u + 0x7FFFu + ((v.u >> 16) & 1u);
  return (u16)(r >> 16);
}
__device__ __forceinline__ float bf2f(u16 h) {
  union { u32 u; float f; } v; v.u = ((u32)h) << 16; return v.f;
}

// ---------------------------------------------------------------------------
// Kernel 1 (round-3 verified, unchanged): per (b, n-tile of 64) block, full C.
// Thread micro-tile 8c x 8n; float4 coalesced loads; register-renaming
// transpose -> short8 16B xbT stores; conflict-free LDS q-reduce; in-wave
// shfl softmax partials (m,l) and pacc; Wv bf16 cast folded into 8 blocks.
// ---------------------------------------------------------------------------
__global__ __launch_bounds__(256) void k_fuse1(const float* __restrict__ x,
                                               const float* __restrict__ W,
                                               u16* __restrict__ xbT,
                                               u16* __restrict__ wvb,
                                               float* __restrict__ pm,
                                               float* __restrict__ pl,
                                               float* __restrict__ pacc) {
  __shared__ float qred[32 * 65];   // 8,320 B, bank-conflict-free
  __shared__ float qred2[4 * 65];   // 1,040 B
  const int t = threadIdx.x;
  const int b = blockIdx.y, n0 = blockIdx.x * 64;
  const int tx = t & 7, ty = t >> 3;        // tx: n-group 0..7, ty: c-group 0..31
  const int c0 = ty * 8, nl = tx * 8;
  const float* xb = x + (size_t)b * NC * NN + n0;

  const float4 w0 = *(const float4*)(W + c0);
  const float4 w1 = *(const float4*)(W + c0 + 4);
  const float wq[8] = {w0.x, w0.y, w0.z, w0.w, w1.x, w1.y, w1.z, w1.w};

  short8 pk[8];          // pk[j] = bf16 x[c0..c0+8][nl+j]  (transposed packs)
  float qp[8] = {0.f, 0.f, 0.f, 0.f, 0.f, 0.f, 0.f, 0.f};

#pragma unroll
  for (int r = 0; r < 8; ++r) {
    const float* xr = xb + (size_t)(c0 + r) * NN + nl;
    const float4 va = *(const float4*)(xr);
    const float4 vb = *(const float4*)(xr + 4);
    qp[0] += wq[r] * va.x; qp[1] += wq[r] * va.y;
    qp[2] += wq[r] * va.z; qp[3] += wq[r] * va.w;
    qp[4] += wq[r] * vb.x; qp[5] += wq[r] * vb.y;
    qp[6] += wq[r] * vb.z; qp[7] += wq[r] * vb.w;
    pk[0][r] = (short)f2bf(va.x); pk[1][r] = (short)f2bf(va.y);
    pk[2][r] = (short)f2bf(va.z); pk[3][r] = (short)f2bf(va.w);
    pk[4][r] = (short)f2bf(vb.x); pk[5][r] = (short)f2bf(vb.y);
    pk[6][r] = (short)f2bf(vb.z); pk[7][r] = (short)f2bf(vb.w);
  }

  u16* ob = xbT + (size_t)(b * NN + n0 + nl) * NC + c0;
#pragma unroll
  for (int j = 0; j < 8; ++j)
    *(short8*)(ob + (size_t)j * NC) = pk[j];

#pragma unroll
  for (int j = 0; j < 8; ++j) qred[ty * 65 + nl + j] = qp[j];
  __syncthreads();
  {
    const int n = t & 63, g = t >> 6;
    float s = 0.f;
#pragma unroll
    for (int k = 0; k < 8; ++k) s += qred[(g * 8 + k) * 65 + n];
    qred2[g * 65 + n] = s;
  }
  __syncthreads();

  float q[8];
#pragma unroll
  for (int j = 0; j < 8; ++j)
    q[j] = qred2[0 * 65 + nl + j] + qred2[1 * 65 + nl + j] +
           qred2[2 * 65 + nl + j] + qred2[3 * 65 + nl + j];

  float m = q[0];
#pragma unroll
  for (int j = 1; j < 8; ++j) m = fmaxf(m, q[j]);
#pragma unroll
  for (int off = 1; off < 8; off <<= 1) m = fmaxf(m, __shfl_xor(m, off));

  float p[8]; float l = 0.f;
#pragma unroll
  for (int j = 0; j < 8; ++j) { p[j] = __expf(q[j] - m); l += p[j]; }
#pragma unroll
  for (int off = 1; off < 8; off <<= 1) l += __shfl_xor(l, off);

  float sc[8];
#pragma unroll
  for (int r = 0; r < 8; ++r) {
    float s = 0.f;
#pragma unroll
    for (int j = 0; j < 8; ++j) s += bf2f((u16)pk[j][r]) * p[j];
    sc[r] = s;
  }
#pragma unroll
  for (int off = 1; off < 8; off <<= 1) {
#pragma unroll
    for (int r = 0; r < 8; ++r) sc[r] += __shfl_xor(sc[r], off);
  }
  if (tx == 0) {
    float* pp = pacc + ((size_t)b * 64 + blockIdx.x) * NC + c0;
#pragma unroll
    for (int r = 0; r < 8; ++r) pp[r] = sc[r];
  }
  if (t == 0) {
    pm[b * 64 + blockIdx.x] = m;
    pl[b * 64 + blockIdx.x] = l;
  }

  if (b == 0 && blockIdx.x < 8) {
    const float* wv = W + (size_t)(1 + ND) * NC;
    const int base = blockIdx.x * 8192;
#pragma unroll
    for (int i = 0; i < 8; ++i) {
      const int idx = base + i * 1024 + t * 4;
      const float4 v = *(const float4*)(wv + idx);
      ushort4 o = {f2bf(v.x), f2bf(v.y), f2bf(v.z), f2bf(v.w)};
      *(ushort4*)(wvb + idx) = o;
    }
  }
}

// ---------------------------------------------------------------------------
// Kernel 2: fused combine + GEMM, 128x128 tile for 4 blocks/CU occupancy.
//  Combine (prologue): redundantly per block, 64 softmax partials -> xs ->
//  ctx (pacc + W via L2).  sctx[t] holds ctx for GLOBAL d = t (0..255).
//  GEMM: bf16 MFMA 16x16x32, BM=128, BN=128, BK=64, 256 threads = 4 waves
//  (2d x 2n).  xbT B-panels read twice across d, second read L3-absorbed.
//  LDS 32KB staging + 2.6KB combine -> 4 blocks/CU, all 1024 blocks
//  co-resident (m97-verified 2-barrier K-loop structure).
//  XOR-swizzled staging (global-source side) + swizzled frag reads.
//  Operand roles swapped: D row = n, col = d -> f32x4 nontemporal stores.
//  FIX vs round 7: epilogue reads sctx[d] (GLOBAL d), not sctx[d - d0].
// ---------------------------------------------------------------------------
#define BM 128
#define BN 128
#define BK 64

__global__ __launch_bounds__(256, 4) void k_gemm(const u16* __restrict__ xbT,
                                                 const u16* __restrict__ wvb,
                                                 const float* __restrict__ W,
                                                 const float* __restrict__ pm,
                                                 const float* __restrict__ pl,
                                                 const float* __restrict__ pacc,
                                                 float* __restrict__ out) {
  __shared__ __align__(16) u16 As[BM * BK];   // 16 KB (Wv rows d0..d0+127)
  __shared__ __align__(16) u16 Bs[BN * BK];   // 16 KB (x cols n0..n0+127)
  __shared__ float am[64], al[64];
  __shared__ __align__(16) float sx[NC];
  __shared__ float sctx[NC];

  const int t = threadIdx.x;
  const int d0 = blockIdx.x * BM;
  const int n0 = blockIdx.y * BN;
  const int b = blockIdx.z;
  const int lane = t & 63, w = t >> 6;
  const int wd = (w & 1) * 64, wn = (w >> 1) * 64;
  const int quad = lane >> 4, l15 = lane & 15;

  // staging addresses (XOR swizzle on the global source, linear LDS dest)
  const int rstg = t >> 3;                               // 0..31
  const int l8 = ((t & 7) ^ (rstg & 7)) * 8;             // logical u16 offset
  const u16* gA = wvb + (size_t)(d0 + rstg) * NC + l8;
  const u16* gB = xbT + (size_t)(b * NN + n0 + rstg) * NC + l8;
  const int ldst = 8 * t;                                // u16 offset in LDS

  // ---- issue K-step 0 staging, combine under its latency ----
#pragma unroll
  for (int i = 0; i < 4; ++i) {
    __builtin_amdgcn_global_load_lds(
        (const __attribute__((address_space(1))) u32*)(gA + (size_t)(32 * i) * NC),
        (__attribute__((address_space(3))) u32*)(As + 2048 * i + ldst), 16, 0, 0);
    __builtin_amdgcn_global_load_lds(
        (const __attribute__((address_space(1))) u32*)(gB + (size_t)(32 * i) * NC),
        (__attribute__((address_space(3))) u32*)(Bs + 2048 * i + ldst), 16, 0, 0);
  }

  if (t < 64) { am[t] = pm[b * 64 + t]; al[t] = pl[b * 64 + t]; }
  __syncthreads();
  float M2 = -3.4e38f;
#pragma unroll
  for (int i = 0; i < 64; ++i) M2 = fmaxf(M2, am[i]);
  {
    float xsv = 0.f, L2s = 0.f;
#pragma unroll 8
    for (int i = 0; i < 64; ++i) {
      const float wgt = __expf(am[i] - M2);
      L2s += wgt * al[i];
      xsv += wgt * pacc[(size_t)(b * 64 + i) * NC + t];
    }
    sx[t] = xsv / L2s;
  }
  __syncthreads();
  {
    const float* wk = W + (size_t)(1 + t) * NC;
    float a = 0.f;
#pragma unroll 4
    for (int c4 = 0; c4 < 64; ++c4) {
      const float4 w4 = *(const float4*)(wk + c4 * 4);
      const float4 s4 = *(const float4*)&sx[c4 * 4];
      a += w4.x * s4.x + w4.y * s4.y + w4.z * s4.z + w4.w * s4.w;
    }
    sctx[t] = a;    // ctx for GLOBAL d = t; visibility via K-loop barriers
  }

  // ---- GEMM main loop (m97 structure: stage, barrier, compute) ----
  f32x4 acc[4][4];   // acc[ni][mi]: ni = n-subtile, mi = d-subtile
#pragma unroll
  for (int ni = 0; ni < 4; ++ni)
#pragma unroll
    for (int mi = 0; mi < 4; ++mi)
      acc[ni][mi] = (f32x4){0.f, 0.f, 0.f, 0.f};

  const int pq0 = ((0 * 4 + quad) ^ (l15 & 7)) * 8;
  const int pq1 = ((1 * 4 + quad) ^ (l15 & 7)) * 8;

  for (int kk = 0; kk < NC; kk += BK) {
    if (kk) {
      __syncthreads();
#pragma unroll
      for (int i = 0; i < 4; ++i) {
        __builtin_amdgcn_global_load_lds(
            (const __attribute__((address_space(1))) u32*)(gA + kk + (size_t)(32 * i) * NC),
            (__attribute__((address_space(3))) u32*)(As + 2048 * i + ldst), 16, 0, 0);
        __builtin_amdgcn_global_load_lds(
            (const __attribute__((address_space(1))) u32*)(gB + kk + (size_t)(32 * i) * NC),
            (__attribute__((address_space(3))) u32*)(Bs + 2048 * i + ldst), 16, 0, 0);
      }
    }
    __syncthreads();

#pragma unroll
    for (int kq = 0; kq < 2; ++kq) {
      const int pq = kq ? pq1 : pq0;
      short8 xf[4], wf[4];
#pragma unroll
      for (int ni = 0; ni < 4; ++ni)       // A-frag: x rows (n)
        xf[ni] = *(const short8*)&Bs[(wn + ni * 16 + l15) * BK + pq];
#pragma unroll
      for (int mi = 0; mi < 4; ++mi)       // B-frag: Wv rows (d)
        wf[mi] = *(const short8*)&As[(wd + mi * 16 + l15) * BK + pq];
#pragma unroll
      for (int ni = 0; ni < 4; ++ni)
#pragma unroll
        for (int mi = 0; mi < 4; ++mi)
          acc[ni][mi] = __builtin_amdgcn_mfma_f32_16x16x32_bf16(xf[ni], wf[mi],
                                                                acc[ni][mi], 0, 0, 0);
    }
  }

  // ---- epilogue: D row = n (quad*4+r), col = d (l15) -> f32x4 stores ----
#pragma unroll
  for (int mi = 0; mi < 4; ++mi) {
    const int d = d0 + wd + mi * 16 + l15;
    const float cx = sctx[d];              // FIX: global d index into sctx
    float* op = out + (size_t)(b * NC + d) * NN + n0 + wn + quad * 4;
#pragma unroll
    for (int ni = 0; ni < 4; ++ni) {
      f32x4 v = acc[ni][mi];
      v[0] = fmaxf(v[0], 0.f) * cx;
      v[1] = fmaxf(v[1], 0.f) * cx;
      v[2] = fmaxf(v[2], 0.f) * cx;
      v[3] = fmaxf(v[3], 0.f) * cx;
      __builtin_nontemporal_store(v, (f32x4*)(op + ni * 16));
    }
  }
}

// ---------------------------------------------------------------------------
extern "C" void kernel_launch(void* const* d_in, const int* in_sizes, int n_in,
                              void* d_out, int out_size, void* d_ws, size_t ws_size,
                              hipStream_t stream) {
  const float* x = (const float*)d_in[0];
  const float* W = (const float*)d_in[1];
  float* out = (float*)d_out;

  char* ws = (char*)d_ws;
  u16* xbT    = (u16*)ws;                                 // 33,554,432 B
  float* pacc = (float*)(ws + 33554432);                  //  1,048,576 B
  float* pm   = (float*)(ws + 34603008);                  //      4,096 B
  float* pl   = (float*)(ws + 34607104);                  //      4,096 B
  u16* wvb    = (u16*)(ws + 34611200);                    //    131,072 B

  k_fuse1<<<dim3(64, 16), 256, 0, stream>>>(x, W, xbT, wvb, pm, pl, pacc);
  k_gemm<<<dim3(2, 32, 16), 256, 0, stream>>>(xbT, wvb, W, pm, pl, pacc, out);
}